// Round 9
// baseline (479.200 us; speedup 1.0000x reference)
//
#include <hip/hip_runtime.h>

#define TT 128
#define BB 64
#define NIN 1024
#define NOUT 2048
#define MR (TT*BB)   // 8192 rows (T*B)

typedef unsigned short u16;
typedef __attribute__((ext_vector_type(8))) __bf16 bf16x8;
typedef __attribute__((ext_vector_type(4))) float f32x4;
typedef __attribute__((ext_vector_type(8))) unsigned short u16x8;

static __device__ __forceinline__ u16 f2bf(float f) {
    union { float f; unsigned u; } v; v.f = f;
    unsigned r = v.u + 0x7fffu + ((v.u >> 16) & 1u);  // RNE
    return (u16)(r >> 16);
}
static __device__ __forceinline__ float bf2f(u16 x) {
    union { unsigned u; float f; } v; v.u = ((unsigned)x) << 16;
    return v.f;
}

// ---- x [M][K] f32 -> chunked bf16 [(K/8)][M][8] ----
__global__ void k_cvt_chunk(const float* __restrict__ s, u16* __restrict__ d, int M_, int K_) {
    __shared__ float t[64][33];
    int m0 = blockIdx.x * 64, k0 = blockIdx.y * 32;
    int ml = threadIdx.x >> 3, kl = (threadIdx.x & 7) * 4;
    #pragma unroll
    for (int p = 0; p < 2; ++p) {
        float4 v = *(const float4*)&s[(size_t)(m0 + ml + p * 32) * K_ + k0 + kl];
        t[ml + p * 32][kl] = v.x; t[ml + p * 32][kl + 1] = v.y;
        t[ml + p * 32][kl + 2] = v.z; t[ml + p * 32][kl + 3] = v.w;
    }
    __syncthreads();
    int q = threadIdx.x >> 6, row = threadIdx.x & 63;
    u16x8 o;
    #pragma unroll
    for (int j = 0; j < 8; ++j) o[j] = f2bf(t[row][q * 8 + j]);
    *(u16x8*)&d[(((size_t)(k0 >> 3) + q) * M_ + m0 + row) * 8] = o;
}

// ---- W [K][N] f32 -> chunked bf16 B^T [(K/8)][OUTM][8] at row offset ----
__global__ void k_wT_chunk(const float* __restrict__ s, u16* __restrict__ d,
                           int K_, int N_, int OUTM, int row_off) {
    __shared__ float t[32][65];
    int k0 = blockIdx.y * 32, n0 = blockIdx.x * 64;
    int kl = threadIdx.x >> 6, nl = threadIdx.x & 63;
    #pragma unroll
    for (int p = 0; p < 8; ++p)
        t[kl + p * 4][nl] = s[(size_t)(k0 + kl + p * 4) * N_ + n0 + nl];
    __syncthreads();
    int q = threadIdx.x >> 6, row = threadIdx.x & 63;
    u16x8 o;
    #pragma unroll
    for (int j = 0; j < 8; ++j) o[j] = f2bf(t[q * 8 + j][row]);
    *(u16x8*)&d[(((size_t)(k0 >> 3) + q) * OUTM + row_off + n0 + row) * 8] = o;
}

__global__ void k_bias_pack(const float* __restrict__ bf_, const float* __restrict__ br_,
                            const float* __restrict__ bcx_, float* __restrict__ ball) {
    int i = blockIdx.x * 256 + threadIdx.x;
    int g = i >> 11, n = i & 2047;
    float v = 0.f;
    if (g == 1) v = bf_[n];
    else if (g == 2) v = br_[n];
    else if (g == 3) v = bcx_[n];
    ball[i] = v;
}

#define GLL16(SRC, DST) __builtin_amdgcn_global_load_lds( \
    (const __attribute__((address_space(1))) void*)(SRC), \
    (__attribute__((address_space(3))) void*)(DST), 16, 0, 0)
#define SBAR() __builtin_amdgcn_s_barrier()
#define SCHED0() __builtin_amdgcn_sched_barrier(0)
#define LGKM0 do { asm volatile("s_waitcnt lgkmcnt(0)" ::: "memory"); SCHED0(); } while (0)
#define VMW(N) asm volatile("s_waitcnt vmcnt(" #N ")" ::: "memory")

// ============ gate GEMM: 8-phase, BM=BN=256, BK=64, 2-dbuf ============
// A [(K/8)][M][8], BT [(K/8)][NB][8] chunked bf16. LDS dbuf (64KB): A0|A1|B0|B1
// regions of 8192 elems (row-halves; chunk(q,row%128)=q*128+row; 0-conflict reads,
// contiguous gll). NOTE (R8 lesson): every LDA phase reads BOTH A regions across
// waves (wr selects region), every LDB phase both B regions (wc>>1). Ledger derived
// from per-wave last-reads: slot0 {B:p2, A:p3}, slot1 {B:p6, A:p7}. Stage order:
// p1:A0(t+1) p2:A1(t+1) p3:B0(t+2) p4:B1(t+2) p5:A0(t+2) p6:A1(t+2) p7:B0(t+3)
// p8:B1(t+3) -- each >=1 barrier-pair after its region's last read. vmcnt(4) at
// p4/p8 (tail: 0) publishes tiles t+1 / t+2.
__global__ __launch_bounds__(512, 2) void k_gemm8(
    const u16* __restrict__ A, const u16* __restrict__ BT,
    const float* __restrict__ bias, u16* __restrict__ outG,
    int M, int NB, int K)
{
    __shared__ __align__(16) u16 L[65536];   // 2 x 32768 elems = 128 KiB

    const int tid = threadIdx.x;
    const int w = tid >> 6, lane = tid & 63;
    const int wr = w >> 2, wc = w & 3;
    const int lr = lane & 15, kq = lane >> 4;
    // XCD column-band swizzle: xcd owns 4 contiguous n-tiles (2MB B slice, L2-fit)
    const int flat = blockIdx.y * gridDim.x + blockIdx.x;
    const int xcd = flat & 7, bi = flat >> 3;
    const int n0 = (xcd * 4 + (bi & 3)) * 256;
    const int m0 = (bi >> 2) * 256;
    const int nk = K >> 6;                   // BK = 64 (nk even)

    // staging bases: chunk c = q*128 + row(0..127); thread covers q=tid>>7 and q+4
    const u16* aS = A + ((size_t)(tid >> 7) * M + m0 + (tid & 127)) * 8;
    const u16* bS = BT + ((size_t)(tid >> 7) * NB + n0 + (tid & 127)) * 8;
    const size_t aT = (size_t)64 * M, bT = (size_t)64 * NB;    // per-K-tile elems
    const size_t aL = (size_t)32 * M, bL = (size_t)32 * NB;    // q+4 elems

    // frag read bases (elem offsets within dbuf slot)
    const int rdA = wr * 8192 + (kq * 128 + lr) * 8;
    const int rdB = 16384 + (wc >> 1) * 8192 + (kq * 128 + (wc & 1) * 64 + lr) * 8;

    f32x4 acc[8][4] = {};
    bf16x8 aA[4][2], bLo[2][2], bHi[2][2];

#define STAGEA(TAU, H) { const size_t _o = (size_t)(TAU) * aT + (H) * 1024; \
    const int _d = (((TAU) & 1) << 15) + ((H) << 13) + w * 512; \
    GLL16(aS + _o, &L[_d]); GLL16(aS + _o + aL, &L[_d + 4096]); }
#define STAGEB(TAU, H) { const size_t _o = (size_t)(TAU) * bT + (H) * 1024; \
    const int _d = (((TAU) & 1) << 15) + 16384 + ((H) << 13) + w * 512; \
    GLL16(bS + _o, &L[_d]); GLL16(bS + _o + bL, &L[_d + 4096]); }
#define LDA(S, H) { _Pragma("unroll") for (int i = 0; i < 4; ++i) \
    _Pragma("unroll") for (int ks = 0; ks < 2; ++ks) \
        aA[i][ks] = *(const bf16x8*)&L[(S) + rdA + ks * 4096 + ((H) * 64 + i * 16) * 8]; }
#define LDB(DST, S, H) { _Pragma("unroll") for (int j = 0; j < 2; ++j) \
    _Pragma("unroll") for (int ks = 0; ks < 2; ++ks) \
        DST[j][ks] = *(const bf16x8*)&L[(S) + rdB + ks * 4096 + ((H) * 32 + j * 16) * 8]; }
#define MM16(BSET, RO, CO) { __builtin_amdgcn_s_setprio(1); \
    _Pragma("unroll") for (int i = 0; i < 4; ++i) \
    _Pragma("unroll") for (int j = 0; j < 2; ++j) \
    _Pragma("unroll") for (int ks = 0; ks < 2; ++ks) \
        acc[(RO) + i][(CO) + j] = __builtin_amdgcn_mfma_f32_16x16x32_bf16( \
            aA[i][ks], BSET[j][ks], acc[(RO) + i][(CO) + j], 0, 0, 0); \
    __builtin_amdgcn_s_setprio(0); }

    // prologue: tile0 complete + tile1 B-halves (12 glls); vmcnt(4) -> tile0 resident
    STAGEB(0, 0); STAGEB(0, 1); STAGEA(0, 0); STAGEA(0, 1);
    STAGEB(1, 0); STAGEB(1, 1);
    VMW(4); SBAR(); SCHED0();

    for (int it = 0; it < nk / 2; ++it) {
        const int t = 2 * it;
        const int s = 0, s1 = 32768;         // t even -> slot0; t+1 -> slot1
        const bool st = (t + 2) < nk;
        // p1: q0 of tile t | stage A0(t+1)
        LDA(s, 0); LDB(bLo, s, 0);
        STAGEA(t + 1, 0);
        SBAR(); LGKM0;
        MM16(bLo, 0, 0);
        SBAR();
        // p2: q1 | stage A1(t+1)  [slot1 A last read prev p7 -> legal]
        LDB(bHi, s, 1);
        STAGEA(t + 1, 1);
        SBAR(); LGKM0;
        MM16(bHi, 0, 2);
        SBAR();
        // p3: q2 | stage B0(t+2)  [slot0 B last read p2 -> legal]
        LDA(s, 1);
        if (st) STAGEB(t + 2, 0);
        SBAR(); LGKM0;
        MM16(bLo, 4, 0);
        SBAR();
        // p4: q3 | stage B1(t+2); publish tile t+1 (vmcnt: 4 = stages after A1(t+1))
        if (st) STAGEB(t + 2, 1);
        MM16(bHi, 4, 2);
        if (st) { VMW(4); } else { VMW(0); }
        SBAR(); SCHED0();
        // p5: q0 of tile t+1 | stage A0(t+2)  [slot0 A last read p3 -> legal]
        LDA(s1, 0); LDB(bLo, s1, 0);
        if (st) STAGEA(t + 2, 0);
        SBAR(); LGKM0;
        MM16(bLo, 0, 0);
        SBAR();
        // p6: q1 | stage A1(t+2)
        LDB(bHi, s1, 1);
        if (st) STAGEA(t + 2, 1);
        SBAR(); LGKM0;
        MM16(bHi, 0, 2);
        SBAR();
        // p7: q2 | stage B0(t+3)  [slot1 B last read p6 -> legal]
        LDA(s1, 1);
        if (st) STAGEB(t + 3, 0);
        SBAR(); LGKM0;
        MM16(bLo, 4, 0);
        SBAR();
        // p8: q3 | stage B1(t+3); publish tile t+2 (vmcnt: 4 = stages after A1(t+2))
        if (st) STAGEB(t + 3, 1);
        MM16(bHi, 4, 2);
        if (st) { VMW(4); } else { VMW(0); }
        SBAR(); SCHED0();
    }
#undef STAGEA
#undef STAGEB
#undef LDA
#undef LDB
#undef MM16

    // epilogue: gates [4][M][2048], sigmoid on g=1,2; C/D map col=lane&15, row=(lane>>4)*4+reg
    const size_t GM2 = (size_t)M << 11;
    #pragma unroll
    for (int i = 0; i < 8; ++i) {
        int r0 = m0 + wr * 128 + i * 16 + kq * 4;
        #pragma unroll
        for (int j = 0; j < 4; ++j) {
            int gc = n0 + wc * 64 + j * 16 + lr;
            float bv = bias[gc];
            int g = gc >> 11;
            bool sig = (g == 1 || g == 2);
            size_t base = (size_t)g * GM2 + (size_t)(gc & 2047);
            #pragma unroll
            for (int q = 0; q < 4; ++q) {
                float v = acc[i][j][q] + bv;
                if (sig) v = 1.f / (1.f + __expf(-v));
                outG[base + (size_t)(r0 + q) * 2048] = f2bf(v);
            }
        }
    }
}

// ============ projection GEMM: BM=128, BN=256, 8 waves (wave tile 64x64) ============
__global__ __launch_bounds__(512, 2) void k_gemm4(
    const u16* __restrict__ A, const u16* __restrict__ BT,
    const float* __restrict__ bias, u16* __restrict__ outC,
    int M, int NB, int K)
{
    constexpr int BM = 128;
    constexpr int BUF = BM * 32 + 8192;
    __shared__ __align__(16) u16 L[4 * BUF];

    const int tid = threadIdx.x;
    const int w = tid >> 6, lane = tid & 63;
    const int wr = w >> 2, wc = w & 3;
    const int lr = lane & 15, kq = lane >> 4;
    const int gx = gridDim.x;
    const int nwg = gx * gridDim.y;
    const int flat = blockIdx.y * gx + blockIdx.x;
    const int swz = (flat & 7) * (nwg >> 3) + (flat >> 3);
    const int m0 = (swz / gx) * BM, n0 = (swz % gx) * 256;
    const int nk = K >> 5;

    const u16* aSrc1; int aDst1;
    {
        int q = tid >> 7, row = tid & 127;
        aSrc1 = A + ((size_t)q * M + m0 + row) * 8;
        aDst1 = (w * 64) * 8;
    }
    const u16* bSrc[2]; int bDst[2];
    #pragma unroll
    for (int l = 0; l < 2; ++l) {
        int tc = tid + l * 512;
        bSrc[l] = BT + ((size_t)(tc >> 8) * NB + n0 + (tc & 255)) * 8;
        bDst[l] = BM * 32 + (w * 64 + l * 512) * 8;
    }
    const size_t aStep = (size_t)32 * M;
    const size_t bStep = (size_t)32 * NB;
    const int rdA = wr * 64 + lr;
    const int rdB = wc * 64 + lr;

    f32x4 acc[4][4] = {};
    bf16x8 aP0[4], bP0[4], aP1[4], bP1[4];

    #pragma unroll
    for (int p = 0; p < 3; ++p) {
        GLL16(aSrc1 + (size_t)p * aStep, &L[p * BUF + aDst1]);
        #pragma unroll
        for (int l = 0; l < 2; ++l) GLL16(bSrc[l] + (size_t)p * bStep, &L[p * BUF + bDst[l]]);
    }
    VMW(3);
    SBAR(); SCHED0();
    #pragma unroll
    for (int i = 0; i < 4; ++i) aP0[i] = *(const bf16x8*)&L[(kq * BM + rdA + i * 16) * 8];
    #pragma unroll
    for (int j = 0; j < 4; ++j) bP0[j] = *(const bf16x8*)&L[BM * 32 + (kq * 256 + rdB + j * 16) * 8];

#define ITER4(KT, CUR, NXT) { \
    const int kt_ = (KT); \
    const int tn = (kt_ + 1 < nk) ? kt_ + 1 : nk - 1; \
    const int nb = (tn & 3) * BUF; \
    if (kt_ + 3 < nk) { \
        const size_t sa = (size_t)(kt_ + 3) * aStep, sb_ = (size_t)(kt_ + 3) * bStep; \
        const int wb = ((kt_ + 3) & 3) * BUF; \
        GLL16(aSrc1 + sa, &L[wb + aDst1]); \
        _Pragma("unroll") for (int l = 0; l < 2; ++l) GLL16(bSrc[l] + sb_, &L[wb + bDst[l]]); \
    } \
    __builtin_amdgcn_s_setprio(1); \
    _Pragma("unroll") for (int i = 0; i < 4; ++i) \
        _Pragma("unroll") for (int j = 0; j < 4; ++j) \
            acc[i][j] = __builtin_amdgcn_mfma_f32_16x16x32_bf16(aP##CUR[i], bP##CUR[j], acc[i][j], 0, 0, 0); \
    _Pragma("unroll") for (int i = 0; i < 4; ++i) \
        aP##NXT[i] = *(const bf16x8*)&L[nb + (kq * BM + rdA + i * 16) * 8]; \
    _Pragma("unroll") for (int j = 0; j < 4; ++j) \
        bP##NXT[j] = *(const bf16x8*)&L[nb + BM * 32 + (kq * 256 + rdB + j * 16) * 8]; \
    __builtin_amdgcn_s_setprio(0); \
    if (kt_ + 3 < nk) { VMW(3); } else { VMW(0); } \
    SBAR(); SCHED0(); }

    for (int kt4 = 0; kt4 < nk; kt4 += 4) {
        ITER4(kt4 + 0, 0, 1);
        ITER4(kt4 + 1, 1, 0);
        ITER4(kt4 + 2, 0, 1);
        ITER4(kt4 + 3, 1, 0);
    }
#undef ITER4

    // epilogue: chunked x2 out: ((gc>>3)*M + r)*8 + (gc&7)
    #pragma unroll
    for (int i = 0; i < 4; ++i) {
        int r0 = m0 + wr * 64 + i * 16 + kq * 4;
        #pragma unroll
        for (int j = 0; j < 4; ++j) {
            int gc = n0 + wc * 64 + j * 16 + lr;
            float bv = bias[gc];
            size_t base = ((size_t)(gc >> 3) * M) * 8 + (size_t)(gc & 7);
            #pragma unroll
            for (int q = 0; q < 4; ++q)
                outC[base + (size_t)(r0 + q) * 8] = f2bf(acc[i][j][q] + bv);
        }
    }
}

// ---- SRU recurrence: one thread per (b,n) chain; hb (if set) written CHUNKED ----
__global__ void k_scan(const u16* __restrict__ G, const float* __restrict__ c0,
                       u16* __restrict__ hb, float* __restrict__ hf,
                       float* __restrict__ cout)
{
    int idx = blockIdx.x * 256 + threadIdx.x;
    int b = idx >> 11, n = idx & 2047;
    float c = c0[idx];
    const size_t GM = (size_t)MR * 2048;
    const size_t hcBase = ((size_t)(n >> 3) * MR) * 8 + (size_t)(n & 7);
    for (int t = 0; t < TT; ++t) {
        int m = t * BB + b;
        size_t p = ((size_t)m << 11) + (size_t)n;
        float xp = bf2f(G[p]);
        float f  = bf2f(G[GM + p]);
        float r  = bf2f(G[2 * GM + p]);
        float cx = bf2f(G[3 * GM + p]);
        c = f * c + (1.f - f) * xp;
        float h = r * tanhf(c) + (1.f - r) * cx;
        if (hb) hb[hcBase + (size_t)m * 8] = f2bf(h);
        if (hf) hf[p] = h;
    }
    if (cout) cout[idx] = c;
}

extern "C" void kernel_launch(void* const* d_in, const int* in_sizes, int n_in,
                              void* d_out, int out_size, void* d_ws, size_t ws_size,
                              hipStream_t stream)
{
    const float* xt  = (const float*)d_in[0];
    const float* ctf = (const float*)d_in[1];
    const float* Wx  = (const float*)d_in[2];
    const float* Wf  = (const float*)d_in[3];
    const float* bfp = (const float*)d_in[4];
    const float* Wr  = (const float*)d_in[5];
    const float* brp = (const float*)d_in[6];
    const float* Wcx = (const float*)d_in[7];
    const float* bcx = (const float*)d_in[8];
    const float* Wcl = (const float*)d_in[9];
    const float* bcl = (const float*)d_in[10];
    float* out = (float*)d_out;

    char* ws = (char*)d_ws;
    u16* x0 = (u16*)ws;       ws += (size_t)MR * NIN * 2;        // chunked
    u16* x2 = (u16*)ws;       ws += (size_t)MR * NIN * 2;        // chunked
    u16* h1 = (u16*)ws;       ws += (size_t)MR * NOUT * 2;       // chunked
    u16* WTall = (u16*)ws;    ws += (size_t)4 * NOUT * NIN * 2;  // chunked
    u16* WclT = (u16*)ws;     ws += (size_t)NIN * NOUT * 2;      // chunked
    float* ball = (float*)ws; ws += (size_t)4 * NOUT * 4;
    u16* G = (u16*)ws;        ws += (size_t)4 * MR * NOUT * 2;   // [4][8192][2048]

    k_cvt_chunk<<<dim3(MR / 64, NIN / 32), 256, 0, stream>>>(xt, x0, MR, NIN);
    k_wT_chunk<<<dim3(NOUT / 64, NIN / 32), 256, 0, stream>>>(Wx,  WTall, NIN, NOUT, 4 * NOUT, 0 * NOUT);
    k_wT_chunk<<<dim3(NOUT / 64, NIN / 32), 256, 0, stream>>>(Wf,  WTall, NIN, NOUT, 4 * NOUT, 1 * NOUT);
    k_wT_chunk<<<dim3(NOUT / 64, NIN / 32), 256, 0, stream>>>(Wr,  WTall, NIN, NOUT, 4 * NOUT, 2 * NOUT);
    k_wT_chunk<<<dim3(NOUT / 64, NIN / 32), 256, 0, stream>>>(Wcx, WTall, NIN, NOUT, 4 * NOUT, 3 * NOUT);
    k_wT_chunk<<<dim3(NIN / 64, NOUT / 32), 256, 0, stream>>>(Wcl, WclT, NOUT, NIN, NIN, 0);
    k_bias_pack<<<32, 256, 0, stream>>>(bfp, brp, bcx, ball);

    // layer 1: fused 4-gate GEMM (NB = 8192, K=1024) + scan (h1 chunked)
    k_gemm8<<<dim3(32, 32), 512, 0, stream>>>(x0, WTall, ball, G, MR, 4 * NOUT, NIN);
    k_scan<<<(BB * NOUT) / 256, 256, 0, stream>>>(G, ctf, h1, (float*)nullptr, (float*)nullptr);

    // inter-layer projection: x2 = h1 @ Wcl + bcl  (grid 4 x 64 = 256)
    k_gemm4<<<dim3(NIN / 256, MR / 128), 512, 0, stream>>>(h1, WclT, bcl, x2, MR, NIN, NOUT);

    // layer 2: gates + scan -> d_out (h2 f32 + c_last)
    k_gemm8<<<dim3(32, 32), 512, 0, stream>>>(x2, WTall, ball, G, MR, 4 * NOUT, NIN);
    k_scan<<<(BB * NOUT) / 256, 256, 0, stream>>>(G, ctf + (size_t)BB * NOUT, (u16*)nullptr, out, out + (size_t)MR * NOUT);
}